// Round 1
// baseline (369.811 us; speedup 1.0000x reference)
//
#include <hip/hip_runtime.h>
#include <cstdint>
#include <cstddef>

typedef _Float16 half8  __attribute__((ext_vector_type(8)));
typedef _Float16 half4v __attribute__((ext_vector_type(4)));
typedef float    f32x4  __attribute__((ext_vector_type(4)));

constexpr int Bc = 4, Tc = 4096, Hc = 16, NBc = 32, Dc = 1024, HIDc = 128;
constexpr int HN = Hc * NBc;      // 512
constexpr int BT = Bc * Tc;       // 16384
constexpr int N1 = 2 * HIDc;      // 256  (h columns: [h1|h2])
// logits N = 1024 (cols 0..511 -> z-head, 512..1023 -> g-head)

// ---------------------------------------------------------------------------
// Kernel 0a: split content_emb (f32) into f16 hi/lo pair (for 3-term MFMA)
// ---------------------------------------------------------------------------
__global__ __launch_bounds__(256) void k_split_x(const float* __restrict__ X,
                                                 _Float16* __restrict__ Xhi,
                                                 _Float16* __restrict__ Xlo) {
  unsigned i = blockIdx.x * 256u + threadIdx.x;      // handles 4 floats
  const float4 x = reinterpret_cast<const float4*>(X)[i];
  float v[4] = {x.x, x.y, x.z, x.w};
  half4v hi, lo;
#pragma unroll
  for (int j = 0; j < 4; j++) {
    _Float16 h = (_Float16)v[j];
    hi[j] = h;
    lo[j] = (_Float16)(v[j] - (float)h);
  }
  reinterpret_cast<half4v*>(Xhi)[i] = hi;
  reinterpret_cast<half4v*>(Xlo)[i] = lo;
}

// ---------------------------------------------------------------------------
// Kernel 0b: build transposed f16 hi/lo weights.
//  W1T [256][1024] : W1T[n][k] = (n<128 ? mw1[k][n] : gw1[k][n-128])
//  W2T [1024][128] : W2T[j][k] = (j<512 ? mw2[k][j] : gw2[k][j-512])
// ---------------------------------------------------------------------------
__global__ __launch_bounds__(256) void k_split_w(
    const float* __restrict__ mw1, const float* __restrict__ gw1,
    const float* __restrict__ mw2, const float* __restrict__ gw2,
    _Float16* __restrict__ W1Thi, _Float16* __restrict__ W1Tlo,
    _Float16* __restrict__ W2Thi, _Float16* __restrict__ W2Tlo) {
  unsigned i = blockIdx.x * 256u + threadIdx.x;
  if (i < 262144u) {                                   // W1T: n in [0,256), k in [0,1024)
    unsigned n = i >> 10, k = i & 1023u;
    float v = (n < 128u) ? mw1[k * 128u + n] : gw1[k * 128u + (n - 128u)];
    _Float16 h = (_Float16)v;
    W1Thi[i] = h;
    W1Tlo[i] = (_Float16)(v - (float)h);
  } else {                                             // W2T: j in [0,1024), k in [0,128)
    unsigned j2 = i - 262144u;
    unsigned n = j2 >> 7, k = j2 & 127u;
    float v = (n < 512u) ? mw2[k * 512u + n] : gw2[k * 512u + (n - 512u)];
    _Float16 h = (_Float16)v;
    W2Thi[j2] = h;
    W2Tlo[j2] = (_Float16)(v - (float)h);
  }
}

// ---------------------------------------------------------------------------
// GEMM1: h[16384][256] = gelu(X @ [mw1|gw1] + [mb1|gb1]); split-f16 MFMA.
// BM=128, BN=64, BK=32.  256 thr = 4 waves (2x2), wave tile 64x32 (4x2 frags).
// ---------------------------------------------------------------------------
__global__ __launch_bounds__(256) void k_gemm1(
    const _Float16* __restrict__ Xhi, const _Float16* __restrict__ Xlo,
    const _Float16* __restrict__ Whi, const _Float16* __restrict__ Wlo,
    const float* __restrict__ mb1, const float* __restrict__ gb1,
    _Float16* __restrict__ Hhi, _Float16* __restrict__ Hlo) {
  __shared__ _Float16 sAh[128][40], sAl[128][40];   // +8 pad: bank-spread, keeps 16B align
  __shared__ _Float16 sBh[64][40],  sBl[64][40];
  const int tid  = threadIdx.x;
  const int lane = tid & 63;
  const int w    = tid >> 6;
  const int wr   = w >> 1, wc = w & 1;
  const int rm   = blockIdx.x * 128;
  const int cn   = blockIdx.y * 64;
  const int lr   = lane & 15, kg = (lane >> 4) * 8;

  f32x4 acc[4][2] = {};

  for (int kt = 0; kt < 1024; kt += 32) {
    // stage A (128 rows x 32 k), 2 sweeps of 64 rows
#pragma unroll
    for (int j = 0; j < 2; j++) {
      int row = j * 64 + (tid >> 2);
      int k0  = (tid & 3) * 8;
      size_t g = (size_t)(rm + row) * 1024 + kt + k0;
      *reinterpret_cast<uint4*>(&sAh[row][k0]) = *reinterpret_cast<const uint4*>(Xhi + g);
      *reinterpret_cast<uint4*>(&sAl[row][k0]) = *reinterpret_cast<const uint4*>(Xlo + g);
    }
    {
      int n  = tid >> 2;
      int k0 = (tid & 3) * 8;
      size_t g = (size_t)(cn + n) * 1024 + kt + k0;
      *reinterpret_cast<uint4*>(&sBh[n][k0]) = *reinterpret_cast<const uint4*>(Whi + g);
      *reinterpret_cast<uint4*>(&sBl[n][k0]) = *reinterpret_cast<const uint4*>(Wlo + g);
    }
    __syncthreads();

    half8 ah[4], al[4], bh[2], bl[2];
#pragma unroll
    for (int m = 0; m < 4; m++) {
      ah[m] = *reinterpret_cast<const half8*>(&sAh[wr * 64 + m * 16 + lr][kg]);
      al[m] = *reinterpret_cast<const half8*>(&sAl[wr * 64 + m * 16 + lr][kg]);
    }
#pragma unroll
    for (int n = 0; n < 2; n++) {
      bh[n] = *reinterpret_cast<const half8*>(&sBh[wc * 32 + n * 16 + lr][kg]);
      bl[n] = *reinterpret_cast<const half8*>(&sBl[wc * 32 + n * 16 + lr][kg]);
    }
#pragma unroll
    for (int m = 0; m < 4; m++)
#pragma unroll
      for (int n = 0; n < 2; n++) {
        acc[m][n] = __builtin_amdgcn_mfma_f32_16x16x32_f16(ah[m], bh[n], acc[m][n], 0, 0, 0);
        acc[m][n] = __builtin_amdgcn_mfma_f32_16x16x32_f16(ah[m], bl[n], acc[m][n], 0, 0, 0);
        acc[m][n] = __builtin_amdgcn_mfma_f32_16x16x32_f16(al[m], bh[n], acc[m][n], 0, 0, 0);
      }
    __syncthreads();
  }

  // epilogue: bias + exact GELU + hi/lo split store
#pragma unroll
  for (int n = 0; n < 2; n++) {
    int colg = cn + wc * 32 + n * 16 + lr;
    float bias = (colg < 128) ? mb1[colg] : gb1[colg - 128];
#pragma unroll
    for (int m = 0; m < 4; m++) {
#pragma unroll
      for (int r = 0; r < 4; r++) {
        int rowg = rm + wr * 64 + m * 16 + (lane >> 4) * 4 + r;
        float v  = acc[m][n][r] + bias;
        float ge = 0.5f * v * (1.0f + erff(v * 0.70710678118654752f));
        _Float16 h = (_Float16)ge;
        Hhi[(size_t)rowg * 256 + colg] = h;
        Hlo[(size_t)rowg * 256 + colg] = (_Float16)(ge - (float)h);
      }
    }
  }
}

// ---------------------------------------------------------------------------
// GEMM2: logits[16384][1024]; cols<512: z = pi*tanh(.)  -> zbuf[row][512]
//                             cols>=512: g = sigmoid(.) -> gout[row][512]
// K = 128 (head-dependent slice of h). Same tile structure, 4 K-steps.
// ---------------------------------------------------------------------------
__global__ __launch_bounds__(256) void k_gemm2(
    const _Float16* __restrict__ Hhi, const _Float16* __restrict__ Hlo,
    const _Float16* __restrict__ Whi, const _Float16* __restrict__ Wlo,
    const float* __restrict__ mb2, const float* __restrict__ gb2,
    float* __restrict__ zbuf, float* __restrict__ gout) {
  __shared__ _Float16 sAh[128][40], sAl[128][40];
  __shared__ _Float16 sBh[64][40],  sBl[64][40];
  const int tid  = threadIdx.x;
  const int lane = tid & 63;
  const int w    = tid >> 6;
  const int wr   = w >> 1, wc = w & 1;
  const int rm   = blockIdx.x * 128;
  const int cn   = blockIdx.y * 64;
  const int khead = (cn < 512) ? 0 : 128;
  const int lr   = lane & 15, kg = (lane >> 4) * 8;

  f32x4 acc[4][2] = {};

  for (int kt = 0; kt < 128; kt += 32) {
#pragma unroll
    for (int j = 0; j < 2; j++) {
      int row = j * 64 + (tid >> 2);
      int k0  = (tid & 3) * 8;
      size_t g = (size_t)(rm + row) * 256 + khead + kt + k0;
      *reinterpret_cast<uint4*>(&sAh[row][k0]) = *reinterpret_cast<const uint4*>(Hhi + g);
      *reinterpret_cast<uint4*>(&sAl[row][k0]) = *reinterpret_cast<const uint4*>(Hlo + g);
    }
    {
      int n  = tid >> 2;
      int k0 = (tid & 3) * 8;
      size_t g = (size_t)(cn + n) * 128 + kt + k0;
      *reinterpret_cast<uint4*>(&sBh[n][k0]) = *reinterpret_cast<const uint4*>(Whi + g);
      *reinterpret_cast<uint4*>(&sBl[n][k0]) = *reinterpret_cast<const uint4*>(Wlo + g);
    }
    __syncthreads();

    half8 ah[4], al[4], bh[2], bl[2];
#pragma unroll
    for (int m = 0; m < 4; m++) {
      ah[m] = *reinterpret_cast<const half8*>(&sAh[wr * 64 + m * 16 + lr][kg]);
      al[m] = *reinterpret_cast<const half8*>(&sAl[wr * 64 + m * 16 + lr][kg]);
    }
#pragma unroll
    for (int n = 0; n < 2; n++) {
      bh[n] = *reinterpret_cast<const half8*>(&sBh[wc * 32 + n * 16 + lr][kg]);
      bl[n] = *reinterpret_cast<const half8*>(&sBl[wc * 32 + n * 16 + lr][kg]);
    }
#pragma unroll
    for (int m = 0; m < 4; m++)
#pragma unroll
      for (int n = 0; n < 2; n++) {
        acc[m][n] = __builtin_amdgcn_mfma_f32_16x16x32_f16(ah[m], bh[n], acc[m][n], 0, 0, 0);
        acc[m][n] = __builtin_amdgcn_mfma_f32_16x16x32_f16(ah[m], bl[n], acc[m][n], 0, 0, 0);
        acc[m][n] = __builtin_amdgcn_mfma_f32_16x16x32_f16(al[m], bh[n], acc[m][n], 0, 0, 0);
      }
    __syncthreads();
  }

  const float PI = 3.14159265358979323846f;
#pragma unroll
  for (int n = 0; n < 2; n++) {
    int colg = cn + wc * 32 + n * 16 + lr;
    bool isz = (colg < 512);
    float bias = isz ? mb2[colg] : gb2[colg - 512];
#pragma unroll
    for (int m = 0; m < 4; m++) {
#pragma unroll
      for (int r = 0; r < 4; r++) {
        int rowg = rm + wr * 64 + m * 16 + (lane >> 4) * 4 + r;
        float v  = acc[m][n][r] + bias;
        if (isz) {
          zbuf[(size_t)rowg * 512 + colg] = PI * tanhf(v);
        } else {
          gout[(size_t)rowg * 512 + (colg - 512)] = 1.0f / (1.0f + expf(-v));
        }
      }
    }
  }
}

// ---------------------------------------------------------------------------
// Scan: 2048 channels (b,h,nb), serial over T=4096.
// wrap(d) = d - 2*pi*rint(d/(2*pi))  ==  atan2(sin d, cos d)
// sigma' = (1-K)(sigma+Q) = K * R_eff   (exact identity)
// 16-deep register prefetch ring hides HBM latency (only 32 waves total).
// NOTE: zbuf aliases out_theta; z[t] is always consumed before theta[t] is
// stored to the same address by the same thread -> no hazard.
// ---------------------------------------------------------------------------
__global__ __launch_bounds__(64) void k_scan(
    const float* __restrict__ tp, const float* __restrict__ zarr,
    const float* __restrict__ garr,
    const float* __restrict__ logQ, const float* __restrict__ logR,
    const float* __restrict__ logS0,
    float* __restrict__ oth, float* __restrict__ osg) {
  const int c  = blockIdx.x * 64 + threadIdx.x;   // 0..2047
  const int b  = c >> 9;
  const int hn = c & 511;
  const unsigned base = (unsigned)b * (unsigned)(Tc * HN) + (unsigned)hn;

  const float Q = expf(logQ[hn]);
  const float R = expf(logR[hn]);
  float sigma   = expf(logS0[hn]);
  float theta = 0.f, tprev = 0.f;

  constexpr float INV2PI = 0.15915494309189535f;
  constexpr float TWOPI  = 6.283185307179586f;
  constexpr int P = 16;

  float ptp[P], pz[P], pg[P];
#pragma unroll
  for (int i = 0; i < P; i++) {
    unsigned idx = base + (unsigned)i * 512u;
    ptp[i] = tp[idx];
    pz[i]  = zarr[idx];
    pg[i]  = garr[idx];
  }

  auto dostep = [&](float tpv, float zv, float gv, unsigned idx) {
    float inc = tpv - tprev; tprev = tpv;
    float thp = theta + inc;
    float s   = sigma + Q;
    float re  = R * __builtin_amdgcn_rcpf(gv + 1e-4f);
    float K   = s * __builtin_amdgcn_rcpf(s + re);
    sigma     = K * re;
    float d   = zv - thp;
    float nr  = rintf(d * INV2PI);
    float innov = __builtin_fmaf(-TWOPI, nr, d);
    theta = __builtin_fmaf(K, innov, thp);
    oth[idx] = theta;
    osg[idx] = sigma;
  };

  for (int tb = 0; tb < Tc - P; tb += P) {
#pragma unroll
    for (int i = 0; i < P; i++) {
      const unsigned idx  = base + (unsigned)(tb + i) * 512u;
      const unsigned pidx = idx + (unsigned)P * 512u;
      float tpv = ptp[i], zv = pz[i], gv = pg[i];
      ptp[i] = tp[pidx];
      pz[i]  = zarr[pidx];
      pg[i]  = garr[pidx];
      dostep(tpv, zv, gv, idx);
    }
  }
#pragma unroll
  for (int i = 0; i < P; i++) {
    const unsigned idx = base + (unsigned)(Tc - P + i) * 512u;
    dostep(ptp[i], pz[i], pg[i], idx);
  }
}

// ---------------------------------------------------------------------------
extern "C" void kernel_launch(void* const* d_in, const int* in_sizes, int n_in,
                              void* d_out, int out_size, void* d_ws, size_t ws_size,
                              hipStream_t stream) {
  const float* theta_path = (const float*)d_in[0];
  const float* X     = (const float*)d_in[1];
  const float* mw1   = (const float*)d_in[2];
  const float* mb1   = (const float*)d_in[3];
  const float* mw2   = (const float*)d_in[4];
  const float* mb2   = (const float*)d_in[5];
  const float* gw1   = (const float*)d_in[6];
  const float* gb1   = (const float*)d_in[7];
  const float* gw2   = (const float*)d_in[8];
  const float* gb2   = (const float*)d_in[9];
  const float* logQ  = (const float*)d_in[10];
  const float* logR  = (const float*)d_in[11];
  const float* logS0 = (const float*)d_in[12];

  const size_t NOUT = (size_t)BT * HN;       // 8,388,608 per output tensor
  float* out_theta = (float*)d_out;
  float* out_sigma = out_theta + NOUT;
  float* out_g     = out_theta + 2 * NOUT;

  // Phase-1 scratch aliases inside d_out (dead by the time they're overwritten):
  _Float16* Xhi = (_Float16*)out_theta;      // 16.7M halves == theta region
  _Float16* Xlo = (_Float16*)out_sigma;      // == sigma region
  float*    zbuf = out_theta;                // z overwrites Xhi after GEMM1 done

  char* ws = (char*)d_ws;
  _Float16* W1Thi = (_Float16*)(ws);
  _Float16* W1Tlo = (_Float16*)(ws + (512u << 10));
  _Float16* W2Thi = (_Float16*)(ws + (1024u << 10));
  _Float16* W2Tlo = (_Float16*)(ws + (1280u << 10));
  _Float16* Hhi   = (_Float16*)(ws + (1536u << 10));
  _Float16* Hlo   = (_Float16*)(ws + (1536u << 10) + (8u << 20));
  // total ws use: ~17.5 MB

  k_split_x<<<16384, 256, 0, stream>>>(X, Xhi, Xlo);
  k_split_w<<<1536, 256, 0, stream>>>(mw1, gw1, mw2, gw2, W1Thi, W1Tlo, W2Thi, W2Tlo);
  k_gemm1<<<dim3(128, 4), 256, 0, stream>>>(Xhi, Xlo, W1Thi, W1Tlo, mb1, gb1, Hhi, Hlo);
  k_gemm2<<<dim3(128, 16), 256, 0, stream>>>(Hhi, Hlo, W2Thi, W2Tlo, mb2, gb2, zbuf, out_g);
  k_scan<<<32, 64, 0, stream>>>(theta_path, zbuf, out_g, logQ, logR, logS0, out_theta, out_sigma);
}

// Round 2
// 297.985 us; speedup vs baseline: 1.2410x; 1.2410x over previous
//
#include <hip/hip_runtime.h>
#include <cstdint>
#include <cstddef>

typedef _Float16 half8  __attribute__((ext_vector_type(8)));
typedef float    f32x4  __attribute__((ext_vector_type(4)));

constexpr int Bc = 4, Tc = 4096, Hc = 16, NBc = 32, Dc = 1024, HIDc = 128;
constexpr int HN = Hc * NBc;      // 512
constexpr int BT = Bc * Tc;       // 16384

// ---------------------------------------------------------------------------
// split helper: 8 f32 -> f16 hi/lo (3-term split-f16 MFMA precision)
// ---------------------------------------------------------------------------
__device__ inline void split8(const float* __restrict__ p,
                              _Float16* __restrict__ dh,
                              _Float16* __restrict__ dl) {
  float4 a = *reinterpret_cast<const float4*>(p);
  float4 b = *reinterpret_cast<const float4*>(p + 4);
  float v[8] = {a.x, a.y, a.z, a.w, b.x, b.y, b.z, b.w};
  half8 hi, lo;
#pragma unroll
  for (int j = 0; j < 8; j++) {
    _Float16 h = (_Float16)v[j];
    hi[j] = h;
    lo[j] = (_Float16)(v[j] - (float)h);
  }
  *reinterpret_cast<half8*>(dh) = hi;
  *reinterpret_cast<half8*>(dl) = lo;
}

// ---------------------------------------------------------------------------
// Kernel: build transposed f16 hi/lo weights.
//  W1T [256][1024] : W1T[n][k] = (n<128 ? mw1[k][n] : gw1[k][n-128])
//  W2T [1024][128] : W2T[j][k] = (j<512 ? mw2[k][j] : gw2[k][j-512])
// ---------------------------------------------------------------------------
__global__ __launch_bounds__(256) void k_split_w(
    const float* __restrict__ mw1, const float* __restrict__ gw1,
    const float* __restrict__ mw2, const float* __restrict__ gw2,
    _Float16* __restrict__ W1Thi, _Float16* __restrict__ W1Tlo,
    _Float16* __restrict__ W2Thi, _Float16* __restrict__ W2Tlo) {
  unsigned i = blockIdx.x * 256u + threadIdx.x;
  if (i < 262144u) {                                   // W1T: n in [0,256), k in [0,1024)
    unsigned n = i >> 10, k = i & 1023u;
    float v = (n < 128u) ? mw1[k * 128u + n] : gw1[k * 128u + (n - 128u)];
    _Float16 h = (_Float16)v;
    W1Thi[i] = h;
    W1Tlo[i] = (_Float16)(v - (float)h);
  } else {                                             // W2T: j in [0,1024), k in [0,128)
    unsigned j2 = i - 262144u;
    unsigned n = j2 >> 7, k = j2 & 127u;
    float v = (n < 512u) ? mw2[k * 512u + n] : gw2[k * 512u + (n - 512u)];
    _Float16 h = (_Float16)v;
    W2Thi[j2] = h;
    W2Tlo[j2] = (_Float16)(v - (float)h);
  }
}

// ---------------------------------------------------------------------------
// GEMM1: h[16384][256] = gelu(X @ [mw1|gw1] + [mb1|gb1]); split-f16 MFMA.
// X is f32, split to hi/lo in-kernel during LDS staging.
// BM=128, BN=64, BK=32.  256 thr = 4 waves (2x2), wave tile 64x32 (4x2 frags).
// ---------------------------------------------------------------------------
__global__ __launch_bounds__(256) void k_gemm1(
    const float* __restrict__ X,
    const _Float16* __restrict__ Whi, const _Float16* __restrict__ Wlo,
    const float* __restrict__ mb1, const float* __restrict__ gb1,
    _Float16* __restrict__ Hhi, _Float16* __restrict__ Hlo) {
  __shared__ _Float16 sAh[128][40], sAl[128][40];   // +8 pad: 80B row stride (16B-aligned)
  __shared__ _Float16 sBh[64][40],  sBl[64][40];
  const int tid  = threadIdx.x;
  const int lane = tid & 63;
  const int w    = tid >> 6;
  const int wr   = w >> 1, wc = w & 1;
  const int rm   = blockIdx.x * 128;
  const int cn   = blockIdx.y * 64;
  const int lr   = lane & 15, kg = (lane >> 4) * 8;

  f32x4 acc[4][2] = {};

  for (int kt = 0; kt < 1024; kt += 32) {
    // stage A (128 rows x 32 k) from f32 X, 2 sweeps of 64 rows
#pragma unroll
    for (int j = 0; j < 2; j++) {
      int row = j * 64 + (tid >> 2);
      int k0  = (tid & 3) * 8;
      size_t g = (size_t)(rm + row) * 1024 + kt + k0;
      split8(X + g, &sAh[row][k0], &sAl[row][k0]);
    }
    {
      int n  = tid >> 2;
      int k0 = (tid & 3) * 8;
      size_t g = (size_t)(cn + n) * 1024 + kt + k0;
      *reinterpret_cast<uint4*>(&sBh[n][k0]) = *reinterpret_cast<const uint4*>(Whi + g);
      *reinterpret_cast<uint4*>(&sBl[n][k0]) = *reinterpret_cast<const uint4*>(Wlo + g);
    }
    __syncthreads();

    half8 ah[4], al[4], bh[2], bl[2];
#pragma unroll
    for (int m = 0; m < 4; m++) {
      ah[m] = *reinterpret_cast<const half8*>(&sAh[wr * 64 + m * 16 + lr][kg]);
      al[m] = *reinterpret_cast<const half8*>(&sAl[wr * 64 + m * 16 + lr][kg]);
    }
#pragma unroll
    for (int n = 0; n < 2; n++) {
      bh[n] = *reinterpret_cast<const half8*>(&sBh[wc * 32 + n * 16 + lr][kg]);
      bl[n] = *reinterpret_cast<const half8*>(&sBl[wc * 32 + n * 16 + lr][kg]);
    }
#pragma unroll
    for (int m = 0; m < 4; m++)
#pragma unroll
      for (int n = 0; n < 2; n++) {
        acc[m][n] = __builtin_amdgcn_mfma_f32_16x16x32_f16(ah[m], bh[n], acc[m][n], 0, 0, 0);
        acc[m][n] = __builtin_amdgcn_mfma_f32_16x16x32_f16(ah[m], bl[n], acc[m][n], 0, 0, 0);
        acc[m][n] = __builtin_amdgcn_mfma_f32_16x16x32_f16(al[m], bh[n], acc[m][n], 0, 0, 0);
      }
    __syncthreads();
  }

  // epilogue: bias + exact GELU + hi/lo split store
#pragma unroll
  for (int n = 0; n < 2; n++) {
    int colg = cn + wc * 32 + n * 16 + lr;
    float bias = (colg < 128) ? mb1[colg] : gb1[colg - 128];
#pragma unroll
    for (int m = 0; m < 4; m++) {
#pragma unroll
      for (int r = 0; r < 4; r++) {
        int rowg = rm + wr * 64 + m * 16 + (lane >> 4) * 4 + r;
        float v  = acc[m][n][r] + bias;
        float ge = 0.5f * v * (1.0f + erff(v * 0.70710678118654752f));
        _Float16 h = (_Float16)ge;
        Hhi[(size_t)rowg * 256 + colg] = h;
        Hlo[(size_t)rowg * 256 + colg] = (_Float16)(ge - (float)h);
      }
    }
  }
}

// ---------------------------------------------------------------------------
// GEMM2: logits[16384][1024]; cols<512: z = pi*tanh(.)  -> zbuf[row][512]
//                             cols>=512: g = sigmoid(.) -> gout[row][512]
// ---------------------------------------------------------------------------
__global__ __launch_bounds__(256) void k_gemm2(
    const _Float16* __restrict__ Hhi, const _Float16* __restrict__ Hlo,
    const _Float16* __restrict__ Whi, const _Float16* __restrict__ Wlo,
    const float* __restrict__ mb2, const float* __restrict__ gb2,
    float* __restrict__ zbuf, float* __restrict__ gout) {
  __shared__ _Float16 sAh[128][40], sAl[128][40];
  __shared__ _Float16 sBh[64][40],  sBl[64][40];
  const int tid  = threadIdx.x;
  const int lane = tid & 63;
  const int w    = tid >> 6;
  const int wr   = w >> 1, wc = w & 1;
  const int rm   = blockIdx.x * 128;
  const int cn   = blockIdx.y * 64;
  const int khead = (cn < 512) ? 0 : 128;
  const int lr   = lane & 15, kg = (lane >> 4) * 8;

  f32x4 acc[4][2] = {};

  for (int kt = 0; kt < 128; kt += 32) {
#pragma unroll
    for (int j = 0; j < 2; j++) {
      int row = j * 64 + (tid >> 2);
      int k0  = (tid & 3) * 8;
      size_t g = (size_t)(rm + row) * 256 + khead + kt + k0;
      *reinterpret_cast<uint4*>(&sAh[row][k0]) = *reinterpret_cast<const uint4*>(Hhi + g);
      *reinterpret_cast<uint4*>(&sAl[row][k0]) = *reinterpret_cast<const uint4*>(Hlo + g);
    }
    {
      int n  = tid >> 2;
      int k0 = (tid & 3) * 8;
      size_t g = (size_t)(cn + n) * 128 + kt + k0;
      *reinterpret_cast<uint4*>(&sBh[n][k0]) = *reinterpret_cast<const uint4*>(Whi + g);
      *reinterpret_cast<uint4*>(&sBl[n][k0]) = *reinterpret_cast<const uint4*>(Wlo + g);
    }
    __syncthreads();

    half8 ah[4], al[4], bh[2], bl[2];
#pragma unroll
    for (int m = 0; m < 4; m++) {
      ah[m] = *reinterpret_cast<const half8*>(&sAh[wr * 64 + m * 16 + lr][kg]);
      al[m] = *reinterpret_cast<const half8*>(&sAl[wr * 64 + m * 16 + lr][kg]);
    }
#pragma unroll
    for (int n = 0; n < 2; n++) {
      bh[n] = *reinterpret_cast<const half8*>(&sBh[wc * 32 + n * 16 + lr][kg]);
      bl[n] = *reinterpret_cast<const half8*>(&sBl[wc * 32 + n * 16 + lr][kg]);
    }
#pragma unroll
    for (int m = 0; m < 4; m++)
#pragma unroll
      for (int n = 0; n < 2; n++) {
        acc[m][n] = __builtin_amdgcn_mfma_f32_16x16x32_f16(ah[m], bh[n], acc[m][n], 0, 0, 0);
        acc[m][n] = __builtin_amdgcn_mfma_f32_16x16x32_f16(ah[m], bl[n], acc[m][n], 0, 0, 0);
        acc[m][n] = __builtin_amdgcn_mfma_f32_16x16x32_f16(al[m], bh[n], acc[m][n], 0, 0, 0);
      }
    __syncthreads();
  }

  const float PI = 3.14159265358979323846f;
#pragma unroll
  for (int n = 0; n < 2; n++) {
    int colg = cn + wc * 32 + n * 16 + lr;
    bool isz = (colg < 512);
    float bias = isz ? mb2[colg] : gb2[colg - 512];
#pragma unroll
    for (int m = 0; m < 4; m++) {
#pragma unroll
      for (int r = 0; r < 4; r++) {
        int rowg = rm + wr * 64 + m * 16 + (lane >> 4) * 4 + r;
        float v  = acc[m][n][r] + bias;
        if (isz) {
          zbuf[(size_t)rowg * 512 + colg] = PI * tanhf(v);
        } else {
          gout[(size_t)rowg * 512 + (colg - 512)] = 1.0f / (1.0f + expf(-v));
        }
      }
    }
  }
}

// ---------------------------------------------------------------------------
// Sigma recurrence as Mobius (LFT) parallel scan over T.
//   sigma' = re*(sigma+Q)/(sigma+Q+re)  ==  M = [[re, re*Q],[1, Q+re]]
// mob1: per (channel, 64-step chunk) compose the 64 step-matrices.
// mob2: per channel, serial stitch of 64 chunk matrices -> sigma at chunk starts.
// mob3: per (channel, chunk) recompute sigma/K per step, store K + sigma out.
// ---------------------------------------------------------------------------
__global__ __launch_bounds__(64) void k_mob1(
    const float* __restrict__ g, const float* __restrict__ logQ,
    const float* __restrict__ logR, float* __restrict__ Mbuf) {
  const int c  = blockIdx.x * 64 + threadIdx.x;   // channel 0..2047
  const int ts = blockIdx.y;                      // chunk 0..63
  const int b  = c >> 9, hn = c & 511;
  const float Q = expf(logQ[hn]);
  const float R = expf(logR[hn]);
  const unsigned base = (unsigned)b * (unsigned)(Tc * HN) + (unsigned)(ts * 64) * (unsigned)HN + (unsigned)hn;

  float ma = 1.f, mb = 0.f, mc = 0.f, md = 1.f;
  float gv[32];
#pragma unroll 1
  for (int ph = 0; ph < 2; ph++) {
#pragma unroll
    for (int j = 0; j < 32; j++) gv[j] = g[base + (unsigned)(ph * 32 + j) * 512u];
#pragma unroll
    for (int j = 0; j < 32; j++) {
      float re = R * __builtin_amdgcn_rcpf(gv[j] + 1e-4f);
      float t1 = __builtin_fmaf(Q, mc, ma);       // a + Q*c
      float t2 = __builtin_fmaf(Q, md, mb);       // b + Q*d
      ma = re * t1;
      mb = re * t2;
      mc = __builtin_fmaf(re, mc, t1);            // t1 + re*c   (old c)
      md = __builtin_fmaf(re, md, t2);            // t2 + re*d   (old d)
      if ((j & 3) == 3) {                         // normalize: re<=2.7e4 -> 4 steps safe
        float r = __builtin_amdgcn_rcpf(md);
        ma *= r; mb *= r; mc *= r; md *= r;
      }
    }
  }
  f32x4 M; M[0] = ma; M[1] = mb; M[2] = mc; M[3] = md;
  reinterpret_cast<f32x4*>(Mbuf)[ts * 2048 + c] = M;
}

__global__ __launch_bounds__(64) void k_mob2(
    const float* __restrict__ Mbuf, const float* __restrict__ logS0,
    float* __restrict__ sstart) {
  const int c  = blockIdx.x * 64 + threadIdx.x;   // 0..2047
  const int hn = c & 511;
  float s = expf(logS0[hn]);
  const f32x4* M4 = reinterpret_cast<const f32x4*>(Mbuf);
  f32x4 ring[8];
#pragma unroll
  for (int i = 0; i < 8; i++) ring[i] = M4[i * 2048 + c];
#pragma unroll
  for (int ts = 0; ts < 64; ts++) {
    sstart[ts * 2048 + c] = s;
    f32x4 M = ring[ts & 7];
    if (ts + 8 < 64) ring[ts & 7] = M4[(ts + 8) * 2048 + c];
    s = (M[0] * s + M[1]) / (M[2] * s + M[3]);    // precise div; only 64 iters
  }
}

__global__ __launch_bounds__(64) void k_mob3(
    const float* __restrict__ g, const float* __restrict__ logQ,
    const float* __restrict__ logR, const float* __restrict__ sstart,
    float* __restrict__ Kbuf, float* __restrict__ osig) {
  const int c  = blockIdx.x * 64 + threadIdx.x;
  const int ts = blockIdx.y;
  const int b  = c >> 9, hn = c & 511;
  const float Q = expf(logQ[hn]);
  const float R = expf(logR[hn]);
  const unsigned base = (unsigned)b * (unsigned)(Tc * HN) + (unsigned)(ts * 64) * (unsigned)HN + (unsigned)hn;

  float s = sstart[ts * 2048 + c];
  float gv[32];
#pragma unroll 1
  for (int ph = 0; ph < 2; ph++) {
#pragma unroll
    for (int j = 0; j < 32; j++) gv[j] = g[base + (unsigned)(ph * 32 + j) * 512u];
#pragma unroll
    for (int j = 0; j < 32; j++) {
      const unsigned idx = base + (unsigned)(ph * 32 + j) * 512u;
      float re = R * __builtin_amdgcn_rcpf(gv[j] + 1e-4f);
      float sp = s + Q;
      float K  = sp * __builtin_amdgcn_rcpf(sp + re);
      s = K * re;                                  // == (1-K)*sp exactly (real arith)
      Kbuf[idx] = K;
      osig[idx] = s;
    }
  }
}

// ---------------------------------------------------------------------------
// Serial theta scan: only the truly-sequential part. 2048 channels, T=4096.
// wrap(d) = d - 2*pi*rint(d/(2*pi))  ==  atan2(sin d, cos d)
// 3 loads (tp, z, K) + 1 store per iter; P=16 register prefetch ring.
// NOTE: zbuf aliases out_theta; z[t] is loaded P iters before theta[t] is
// stored to the same address by the same thread -> in-order, no hazard.
// ---------------------------------------------------------------------------
__global__ __launch_bounds__(64) void k_scan_theta(
    const float* __restrict__ tp, const float* __restrict__ zarr,
    const float* __restrict__ Karr, float* __restrict__ oth) {
  const int c  = blockIdx.x * 64 + threadIdx.x;   // 0..2047
  const int b  = c >> 9;
  const int hn = c & 511;
  const unsigned base = (unsigned)b * (unsigned)(Tc * HN) + (unsigned)hn;

  float theta = 0.f, tprev = 0.f;

  constexpr float INV2PI = 0.15915494309189535f;
  constexpr float TWOPI  = 6.283185307179586f;
  constexpr int P = 16;

  float ptp[P], pz[P], pK[P];
#pragma unroll
  for (int i = 0; i < P; i++) {
    unsigned idx = base + (unsigned)i * 512u;
    ptp[i] = tp[idx];
    pz[i]  = zarr[idx];
    pK[i]  = Karr[idx];
  }

  auto dostep = [&](float tpv, float zv, float Kv, unsigned idx) {
    float inc = tpv - tprev; tprev = tpv;
    float thp = theta + inc;
    float d   = zv - thp;
    float nr  = rintf(d * INV2PI);
    float innov = __builtin_fmaf(-TWOPI, nr, d);
    theta = __builtin_fmaf(Kv, innov, thp);
    oth[idx] = theta;
  };

  for (int tb = 0; tb < Tc - P; tb += P) {
#pragma unroll
    for (int i = 0; i < P; i++) {
      const unsigned idx  = base + (unsigned)(tb + i) * 512u;
      const unsigned pidx = idx + (unsigned)P * 512u;
      float tpv = ptp[i], zv = pz[i], Kv = pK[i];
      ptp[i] = tp[pidx];
      pz[i]  = zarr[pidx];
      pK[i]  = Karr[pidx];
      dostep(tpv, zv, Kv, idx);
    }
  }
#pragma unroll
  for (int i = 0; i < P; i++) {
    const unsigned idx = base + (unsigned)(Tc - P + i) * 512u;
    dostep(ptp[i], pz[i], pK[i], idx);
  }
}

// ---------------------------------------------------------------------------
extern "C" void kernel_launch(void* const* d_in, const int* in_sizes, int n_in,
                              void* d_out, int out_size, void* d_ws, size_t ws_size,
                              hipStream_t stream) {
  const float* theta_path = (const float*)d_in[0];
  const float* X     = (const float*)d_in[1];
  const float* mw1   = (const float*)d_in[2];
  const float* mb1   = (const float*)d_in[3];
  const float* mw2   = (const float*)d_in[4];
  const float* mb2   = (const float*)d_in[5];
  const float* gw1   = (const float*)d_in[6];
  const float* gb1   = (const float*)d_in[7];
  const float* gw2   = (const float*)d_in[8];
  const float* gb2   = (const float*)d_in[9];
  const float* logQ  = (const float*)d_in[10];
  const float* logR  = (const float*)d_in[11];
  const float* logS0 = (const float*)d_in[12];

  const size_t NOUT = (size_t)BT * HN;       // 8,388,608 per output tensor
  float* out_theta = (float*)d_out;
  float* out_sigma = out_theta + NOUT;
  float* out_g     = out_theta + 2 * NOUT;

  float* zbuf = out_theta;   // z written by gemm2, consumed by scan before theta store

  char* ws = (char*)d_ws;
  _Float16* W1Thi = (_Float16*)(ws);                              // 512 KB
  _Float16* W1Tlo = (_Float16*)(ws + (512u << 10));               // 512 KB
  _Float16* W2Thi = (_Float16*)(ws + (1024u << 10));              // 256 KB
  _Float16* W2Tlo = (_Float16*)(ws + (1280u << 10));              // 256 KB
  _Float16* Hhi   = (_Float16*)(ws + (1536u << 10));              // 8 MB
  _Float16* Hlo   = (_Float16*)(ws + (1536u << 10) + (8u << 20)); // 8 MB
  float*    Mbuf  = (float*)  (ws + (1536u << 10) + (16u << 20)); // 2 MB
  float*    sst   = (float*)  (ws + (1536u << 10) + (18u << 20)); // 512 KB
  float*    Kbuf  = (float*)  (ws + (2048u << 10) + (18u << 20)); // 32 MB
  // total ws use ~52 MB

  k_split_w<<<1536, 256, 0, stream>>>(mw1, gw1, mw2, gw2, W1Thi, W1Tlo, W2Thi, W2Tlo);
  k_gemm1<<<dim3(128, 4), 256, 0, stream>>>(X, W1Thi, W1Tlo, mb1, gb1, Hhi, Hlo);
  k_gemm2<<<dim3(128, 16), 256, 0, stream>>>(Hhi, Hlo, W2Thi, W2Tlo, mb2, gb2, zbuf, out_g);
  k_mob1<<<dim3(32, 64), 64, 0, stream>>>(out_g, logQ, logR, Mbuf);
  k_mob2<<<32, 64, 0, stream>>>(Mbuf, logS0, sst);
  k_mob3<<<dim3(32, 64), 64, 0, stream>>>(out_g, logQ, logR, sst, Kbuf, out_sigma);
  k_scan_theta<<<32, 64, 0, stream>>>(theta_path, zbuf, Kbuf, out_theta);
}